// Round 3
// baseline (562.498 us; speedup 1.0000x reference)
//
#include <hip/hip_runtime.h>
#include <stdint.h>

// YoloNAS postprocess, fp32 in/out.
// conf/argmax -> 32k-bin histogram select -> candidate compact -> exact bitonic
// sort (conf desc, idx asc) -> top-1024 -> class-offset IoU bit matrix -> greedy sweep.
// All NMS arithmetic in exact fp32 (explicit __f*_rn, no FMA contraction) to match numpy ref.
// Crash root cause from R1/R2: inputs are fp32 (not bf16); all data-dependent indices now clamped.

#define N_ANCH   262144
#define N_CLS    80
#define K_TOP    1024
#define NBIN2    32769        // bins over conf bits: (u - 0x3F000000) >> 8, conf in [0.5, 1.0]
#define CAP      4096         // candidate list capacity (expected ~1.3k)

// ---- workspace layout (bytes); total 340096 < proven ws_size >= 836608 ----
#define OFF_SCAL  0           // int32[16]: [0]=cT bin, [2]=nsel, [3]=candidate counter
#define OFF_HIST  64          // uint32[32769]
#define OFF_LIST  131200      // uint64[4096] sort keys
#define OFF_TB    163968      // float4[1024] top boxes
#define OFF_TC    180352      // float[1024] top conf
#define OFF_TL    184448      // float[1024] top label
#define OFF_OB    188544      // float4[1024] offset boxes
#define OFF_AREA  204928      // float[1024] areas of offset boxes
#define OFF_MASK  209024      // uint64[1024][16] suppression bit matrix
#define WS_REQUIRED 340096

// ---------- kernel 0: zero scal + hist (ws poisoned 0xAA) ----------
__global__ __launch_bounds__(256) void k_zero(uint32_t* __restrict__ w) {
    w[blockIdx.x * 256 + threadIdx.x] = 0u;   // 129 blocks: 33024 words; spill lands in LIST (no init needed)
}

// ---------- sentinel: report ws_size (KiB) via absmax if scratch too small ----------
__global__ __launch_bounds__(256) void k_sentinel(float* __restrict__ out, float v) {
    int i = blockIdx.x * 256 + threadIdx.x;
    if (i < K_TOP * 6) out[i] = v;
}

// per-anchor conf/argmax over 80 fp32 scores (first-max = jnp.argmax semantics)
static __device__ __forceinline__ void conf_argmax(const float* __restrict__ scores,
                                                   int a, float& best, int& lab) {
    const float4* p = (const float4*)(scores + (size_t)a * N_CLS);
    best = -1.f; lab = 0;
    #pragma unroll
    for (int i = 0; i < 20; i++) {
        float4 w = p[i];
        if (w.x > best) { best = w.x; lab = 4 * i; }
        if (w.y > best) { best = w.y; lab = 4 * i + 1; }
        if (w.z > best) { best = w.z; lab = 4 * i + 2; }
        if (w.w > best) { best = w.w; lab = 4 * i + 3; }
    }
}

static __device__ __forceinline__ uint32_t conf_key24(float best) {
    uint32_t u = __float_as_uint(best);
    if (u > 0x3F800000u) u = 0x3F800000u;    // clamp (defensive; conf <= 1.0 for real data)
    return u - 0x3F000000u;                  // 0..0x800000, monotone in conf
}

// ---------- kernel 1: histogram of conf high-bits ----------
__global__ __launch_bounds__(256) void k_hist(const float* __restrict__ scores,
                                              uint32_t* __restrict__ hist) {
    const int a = blockIdx.x * 256 + threadIdx.x;
    float best; int lab;
    conf_argmax(scores, a, best, lab);
    if (best >= 0.5f) {
        uint32_t bin = conf_key24(best) >> 8;    // 0..32768, in bounds by clamp
        atomicAdd(&hist[bin], 1u);
    }
}

// ---------- kernel 2: suffix-scan 32769 bins -> cutoff bin cT, nsel ----------
__global__ __launch_bounds__(1024) void k_scan(const uint32_t* __restrict__ hist,
                                               int32_t* __restrict__ scal) {
    __shared__ uint32_t part[1024];
    __shared__ uint32_t suf[1024];
    const int t = threadIdx.x;
    const int lo = t * 33;
    const int hi = (lo + 33 < NBIN2) ? lo + 33 : NBIN2;   // seg [lo, hi)
    uint32_t s = 0;
    for (int b = lo; b < hi; b++) s += hist[b];
    part[t] = s; suf[t] = s;
    __syncthreads();
    for (int off = 1; off < 1024; off <<= 1) {            // inclusive suffix scan
        uint32_t v = (t + off < 1024) ? suf[t + off] : 0;
        __syncthreads();
        suf[t] += v;
        __syncthreads();
    }
    // crossing bin: run(above) < K <= run+cnt  (unique; only exists if total >= K)
    uint32_t run = suf[t] - part[t];                      // count in bins above this segment
    for (int b = hi - 1; b >= lo; b--) {
        uint32_t c = hist[b];
        if (run < K_TOP && run + c >= K_TOP) scal[0] = b; // cT (scal[0] pre-zeroed: default 0)
        run += c;
    }
    if (t == 0) {
        uint32_t total = suf[0];
        ((uint32_t*)scal)[2] = (total < K_TOP) ? total : K_TOP;   // nsel
    }
}

// ---------- kernel 3: emit candidates (bin >= cT) with exact sort keys ----------
__global__ __launch_bounds__(256) void k_cand(const float* __restrict__ scores,
                                              const int32_t* __restrict__ scal,
                                              uint32_t* __restrict__ counter,  // &scal[3]
                                              unsigned long long* __restrict__ list) {
    const int a = blockIdx.x * 256 + threadIdx.x;
    const uint32_t cT = (uint32_t)scal[0];
    float best; int lab;
    conf_argmax(scores, a, best, lab);
    if (best >= 0.5f) {
        uint32_t key24 = conf_key24(best);
        if ((key24 >> 8) >= cT) {
            uint32_t slot = atomicAdd(counter, 1u);
            if (slot < CAP) {
                // ascending sort => conf desc then idx asc: keyp = 0x1000000 - key24 (25b)
                unsigned long long sk =
                    ((unsigned long long)(0x1000000u - key24) << 25) |
                    ((unsigned long long)(uint32_t)a << 7) |
                    (unsigned long long)(uint32_t)lab;
                list[slot] = sk;
            }
        }
    }
}

// ---------- kernel 4: bitonic sort 4096 keys, gather top-1024 ----------
__global__ __launch_bounds__(1024) void k_sort(const unsigned long long* __restrict__ list,
                                               const int32_t* __restrict__ scal,
                                               const float4* __restrict__ bboxes,
                                               float4* __restrict__ topBox,
                                               float* __restrict__ topConf,
                                               float* __restrict__ topLab) {
    __shared__ unsigned long long sk[CAP];
    const int t = threadIdx.x;
    uint32_t ncand = ((const uint32_t*)scal)[3];
    if (ncand > CAP) ncand = CAP;
    const uint32_t nsel = ((const uint32_t*)scal)[2];
    for (int i = t; i < CAP; i += 1024) sk[i] = (i < (int)ncand) ? list[i] : ~0ull;
    __syncthreads();
    for (int k = 2; k <= CAP; k <<= 1) {
        for (int j = k >> 1; j > 0; j >>= 1) {
            #pragma unroll
            for (int r0 = 0; r0 < 4; r0++) {
                int e = t + r0 * 1024;
                int p = e ^ j;
                if (p > e) {
                    unsigned long long x = sk[e], y = sk[p];
                    bool up = ((e & k) == 0);
                    if (up ? (x > y) : (x < y)) { sk[e] = y; sk[p] = x; }
                }
            }
            __syncthreads();
        }
    }
    // t in [0, 1024): rank t
    unsigned long long s = sk[t];
    float4 bx = make_float4(0.f, 0.f, 0.f, 0.f);
    float cf = 0.f, lb = 0.f;
    if ((uint32_t)t < nsel) {
        uint32_t idx  = (uint32_t)(s >> 7) & 0x3FFFFu;     // < 262144 by construction
        uint32_t lab  = (uint32_t)s & 127u;
        uint32_t keyp = (uint32_t)(s >> 25);
        uint32_t u    = 0x3F000000u + (0x1000000u - keyp);  // exact conf bits
        cf = __uint_as_float(u);
        lb = (float)lab;
        bx = bboxes[idx];
    }
    topBox[t] = bx; topConf[t] = cf; topLab[t] = lb;
}

// ---------- kernel 5: max_coord, offset boxes, areas (exact reference fp32 order) ----------
__global__ __launch_bounds__(1024) void k_prep(const float4* __restrict__ topBox,
                                               const float* __restrict__ topLab,
                                               float4* __restrict__ ob,
                                               float* __restrict__ area) {
    __shared__ float red[1024];
    const int t = threadIdx.x;
    float4 bx = topBox[t];
    red[t] = fmaxf(fmaxf(bx.x, bx.y), fmaxf(bx.z, bx.w));
    __syncthreads();
    for (int off = 512; off > 0; off >>= 1) {
        if (t < off) red[t] = fmaxf(red[t], red[t + off]);
        __syncthreads();
    }
    float M = __fadd_rn(red[0], 1.0f);
    float o = __fmul_rn(topLab[t], M);
    float4 q;
    q.x = __fadd_rn(bx.x, o); q.y = __fadd_rn(bx.y, o);
    q.z = __fadd_rn(bx.z, o); q.w = __fadd_rn(bx.w, o);
    ob[t] = q;
    area[t] = __fmul_rn(__fsub_rn(q.z, q.x), __fsub_rn(q.w, q.y));
}

// ---------- kernel 6: pairwise IoU suppression bit matrix ----------
__global__ __launch_bounds__(256) void k_mask(const float4* __restrict__ ob,
                                              const float* __restrict__ area,
                                              unsigned long long* __restrict__ mask) {
    __shared__ float4 sob[K_TOP];
    __shared__ float  sar[K_TOP];
    const int t = threadIdx.x, b = blockIdx.x;
    for (int i = t; i < K_TOP; i += 256) { sob[i] = ob[i]; sar[i] = area[i]; }
    __syncthreads();
    const int il = t >> 4;            // row within block (0..15)
    const int w  = t & 15;            // 64-bit word (0..15)
    const int i  = b * 16 + il;
    const float4 bi = sob[i];
    const float  ai = sar[i];
    unsigned long long word = 0;
    const int j0 = w * 64;
    #pragma unroll 8
    for (int bit = 0; bit < 64; bit++) {
        const int j = j0 + bit;
        if (j > i) {
            float4 bj = sob[j];
            float lx = fmaxf(bi.x, bj.x), ly = fmaxf(bi.y, bj.y);
            float rx = fminf(bi.z, bj.z), ry = fminf(bi.w, bj.w);
            float wx = fmaxf(__fsub_rn(rx, lx), 0.f);
            float wy = fmaxf(__fsub_rn(ry, ly), 0.f);
            float inter = __fmul_rn(wx, wy);
            float uni = __fsub_rn(__fadd_rn(ai, sar[j]), inter);
            float iou = __fdiv_rn(inter, fmaxf(uni, 1e-9f));
            if (iou > 0.6f) word |= 1ull << bit;
        }
    }
    mask[i * 16 + w] = word;
}

// ---------- kernel 7: serial greedy sweep + masked fp32 output ----------
__global__ __launch_bounds__(1024) void k_sweep(const unsigned long long* __restrict__ mask,
                                                const int32_t* __restrict__ scal,
                                                const float4* __restrict__ topBox,
                                                const float* __restrict__ topConf,
                                                const float* __restrict__ topLab,
                                                float* __restrict__ out) {
    __shared__ unsigned long long keepw[16];
    const int t = threadIdx.x;
    const uint32_t nsel = ((const uint32_t*)scal)[2];
    if (t < 64) {
        unsigned long long kw = 0;
        if (t < 16) {
            int lo = t * 64;
            kw = (nsel >= (uint32_t)(lo + 64)) ? ~0ull
               : ((nsel <= (uint32_t)lo) ? 0ull : ((1ull << (nsel - lo)) - 1ull));
        }
        for (int i = 0; i < K_TOP; i++) {
            unsigned long long cur = __shfl(kw, i >> 6);
            unsigned long long bi = (cur >> (i & 63)) & 1ull;
            unsigned long long m = (t < 16) ? mask[i * 16 + t] : 0ull;
            kw &= ~(m & (0ull - bi));      // branchless: apply row i's suppression iff keep[i]
        }
        if (t < 16) keepw[t] = kw;
    }
    __syncthreads();
    const bool keep = (keepw[t >> 6] >> (t & 63)) & 1ull;
    float4 bx = topBox[t];
    float v0 = keep ? bx.x : 0.f, v1 = keep ? bx.y : 0.f;
    float v2 = keep ? bx.z : 0.f, v3 = keep ? bx.w : 0.f;
    float v4 = keep ? topConf[t] : 0.f, v5 = keep ? topLab[t] : 0.f;
    float2* o2 = (float2*)out;            // row base 6t floats -> 8B aligned
    o2[t * 3 + 0] = make_float2(v0, v1);
    o2[t * 3 + 1] = make_float2(v2, v3);
    o2[t * 3 + 2] = make_float2(v4, v5);
}

extern "C" void kernel_launch(void* const* d_in, const int* in_sizes, int n_in,
                              void* d_out, int out_size, void* d_ws, size_t ws_size,
                              hipStream_t stream) {
    // inputs per setup_inputs() order; defensively identify by size (scores is 20x larger)
    const float* bboxes = (const float*)d_in[0];
    const float* scores = (const float*)d_in[1];
    if (n_in >= 2 && in_sizes[0] > in_sizes[1]) {
        bboxes = (const float*)d_in[1];
        scores = (const float*)d_in[0];
    }
    char* ws = (char*)d_ws;

    if (ws_size < (size_t)WS_REQUIRED) {
        k_sentinel<<<(K_TOP * 6 + 255) / 256, 256, 0, stream>>>(
            (float*)d_out, (float)(ws_size >> 10));
        return;
    }

    int32_t*  scal    = (int32_t*)(ws + OFF_SCAL);
    uint32_t* hist    = (uint32_t*)(ws + OFF_HIST);
    unsigned long long* list = (unsigned long long*)(ws + OFF_LIST);
    float4*   topBox  = (float4*)(ws + OFF_TB);
    float*    topConf = (float*)(ws + OFF_TC);
    float*    topLab  = (float*)(ws + OFF_TL);
    float4*   ob      = (float4*)(ws + OFF_OB);
    float*    area    = (float*)(ws + OFF_AREA);
    unsigned long long* mask = (unsigned long long*)(ws + OFF_MASK);

    k_zero <<<129,           256, 0, stream>>>((uint32_t*)ws);
    k_hist <<<N_ANCH / 256,  256, 0, stream>>>(scores, hist);
    k_scan <<<1,            1024, 0, stream>>>(hist, scal);
    k_cand <<<N_ANCH / 256,  256, 0, stream>>>(scores, scal, (uint32_t*)&scal[3], list);
    k_sort <<<1,            1024, 0, stream>>>(list, scal, (const float4*)bboxes,
                                               topBox, topConf, topLab);
    k_prep <<<1,            1024, 0, stream>>>(topBox, topLab, ob, area);
    k_mask <<<64,            256, 0, stream>>>(ob, area, mask);
    k_sweep<<<1,            1024, 0, stream>>>(mask, scal, topBox, topConf, topLab,
                                               (float*)d_out);
}

// Round 4
// 327.872 us; speedup vs baseline: 1.7156x; 1.7156x over previous
//
#include <hip/hip_runtime.h>
#include <stdint.h>

// YoloNAS postprocess, fp32 in/out.
// R4: single score pass (bins16 sidecar), LDS-staged readlane NMS sweep, prep fused into sort,
// mask overlaps dead hist region. Exact fp32 NMS arithmetic (no FMA contraction) as in R3 (absmax 0).

#define N_ANCH   262144
#define N_CLS    80
#define K_TOP    1024
#define NBIN2    32768        // bins = min((u - 0x3F000000) >> 8, 32767)
#define CAP      4096         // candidate list capacity (expected ~1.3k)

// ---- workspace layout (bytes); total 733248 < proven ws_size >= 836608 ----
#define OFF_SCAL  0           // int32[16]: [0]=cT bin, [2]=nsel, [3]=candidate counter
#define OFF_HIST  64          // uint32[32768] -- dead after k_scan
#define OFF_MASK  64          // uint64[1024][16] suppression bits (overlaps HIST; written by k_mask)
#define OFF_BINS  131136      // uint16[262144] per-anchor bin
#define OFF_LIST  655424      // uint64[4096] sort keys
#define OFF_TB    688192      // float4[1024] top boxes
#define OFF_TC    704576      // float[1024] top conf
#define OFF_TL    708672      // float[1024] top label
#define OFF_OB    712768      // float4[1024] offset boxes
#define OFF_AREA  729152      // float[1024] areas of offset boxes
#define WS_REQUIRED 733248
#define ZERO_WORDS 32784      // SCAL + HIST = 131136 B (k_zero may spill into BINS: rewritten by k_conf)

// ---------- kernel 0: zero scal + hist (ws poisoned 0xAA) ----------
__global__ __launch_bounds__(256) void k_zero(uint32_t* __restrict__ w) {
    uint32_t i = blockIdx.x * 256 + threadIdx.x;
    w[i] = 0u;                // 129 blocks x 256 = 33024 words >= ZERO_WORDS
}

// ---------- sentinel: report ws_size (KiB) via absmax if scratch too small ----------
__global__ __launch_bounds__(256) void k_sentinel(float* __restrict__ out, float v) {
    int i = blockIdx.x * 256 + threadIdx.x;
    if (i < K_TOP * 6) out[i] = v;
}

static __device__ __forceinline__ uint32_t conf_key24(float best) {
    uint32_t u = __float_as_uint(best);
    if (u > 0x3F800000u) u = 0x3F800000u;    // defensive clamp; conf in [0.5, 1)
    if (u < 0x3F000000u) u = 0x3F000000u;
    return u - 0x3F000000u;                  // 0..0x800000, monotone in conf
}

// ---------- kernel 1: conf/argmax (4 lanes per anchor) + hist + per-anchor bin ----------
__global__ __launch_bounds__(256) void k_conf(const float* __restrict__ scores,
                                              uint16_t* __restrict__ bins16,
                                              uint32_t* __restrict__ hist) {
    const int t = threadIdx.x;
    const int g = t >> 2;                    // anchor group in block (0..63)
    const int s = t & 3;                     // sublane
    const int a = blockIdx.x * 64 + g;
    const float4* row = (const float4*)(scores + (size_t)a * N_CLS);
    float best = -1.f; int lab = 0;
    #pragma unroll
    for (int i = 0; i < 5; i++) {
        float4 w = row[s + i * 4];           // 64B-contiguous per 4-lane group
        const int c0 = (s + i * 4) * 4;
        if (w.x > best) { best = w.x; lab = c0; }
        if (w.y > best) { best = w.y; lab = c0 + 1; }
        if (w.z > best) { best = w.z; lab = c0 + 2; }
        if (w.w > best) { best = w.w; lab = c0 + 3; }
    }
    // first-max tie-break: larger conf, then smaller class
    unsigned long long key = ((unsigned long long)(uint32_t)__float_as_uint(best) << 7)
                           | (unsigned long long)(uint32_t)(127 - lab);
    unsigned long long o1 = __shfl_xor(key, 1); if (o1 > key) key = o1;
    unsigned long long o2 = __shfl_xor(key, 2); if (o2 > key) key = o2;
    if (s == 0) {
        float bv = __uint_as_float((uint32_t)(key >> 7));
        uint32_t bin = 0;
        if (bv >= 0.5f) {
            bin = conf_key24(bv) >> 8;
            if (bin > 32767u) bin = 32767u;
            atomicAdd(&hist[bin], 1u);
        }
        bins16[a] = (uint16_t)bin;           // bin 0 also used for rejects; k_cand re-verifies
    }
}

// ---------- kernel 2: suffix-scan 32768 bins -> cutoff bin cT, nsel ----------
__global__ __launch_bounds__(1024) void k_scan(const uint32_t* __restrict__ hist,
                                               int32_t* __restrict__ scal) {
    __shared__ uint32_t part[1024];
    __shared__ uint32_t suf[1024];
    const int t = threadIdx.x;
    const int lo = t * 32;
    uint32_t s = 0;
    for (int b = lo; b < lo + 32; b++) s += hist[b];
    part[t] = s; suf[t] = s;
    __syncthreads();
    for (int off = 1; off < 1024; off <<= 1) {            // inclusive suffix scan
        uint32_t v = (t + off < 1024) ? suf[t + off] : 0;
        __syncthreads();
        suf[t] += v;
        __syncthreads();
    }
    uint32_t run = suf[t] - part[t];                      // count in bins above this segment
    for (int b = lo + 31; b >= lo; b--) {
        uint32_t c = hist[b];
        if (run < K_TOP && run + c >= K_TOP) scal[0] = b; // unique crossing; default 0 (pre-zeroed)
        run += c;
    }
    if (t == 0) {
        uint32_t total = suf[0];
        ((uint32_t*)scal)[2] = (total < K_TOP) ? total : K_TOP;   // nsel
    }
}

// ---------- kernel 3: scan bins16, recompute exact key for hits, emit candidates ----------
__global__ __launch_bounds__(256) void k_cand(const float* __restrict__ scores,
                                              const uint16_t* __restrict__ bins16,
                                              const int32_t* __restrict__ scal,
                                              uint32_t* __restrict__ counter,   // &scal[3]
                                              unsigned long long* __restrict__ list) {
    const int tid = blockIdx.x * 256 + threadIdx.x;       // 32768 threads x 8 bins
    const uint32_t cT = (uint32_t)scal[0];
    uint4 v = ((const uint4*)bins16)[tid];
    uint32_t wv[4] = {v.x, v.y, v.z, v.w};
    #pragma unroll
    for (int k = 0; k < 8; k++) {
        uint32_t bin = (wv[k >> 1] >> ((k & 1) * 16)) & 0xFFFFu;
        if (bin >= cT) {
            const int a = tid * 8 + k;
            const float4* row = (const float4*)(scores + (size_t)a * N_CLS);
            float best = -1.f; int lab = 0;
            for (int f = 0; f < 20; f++) {
                float4 w = row[f];
                if (w.x > best) { best = w.x; lab = 4 * f; }
                if (w.y > best) { best = w.y; lab = 4 * f + 1; }
                if (w.z > best) { best = w.z; lab = 4 * f + 2; }
                if (w.w > best) { best = w.w; lab = 4 * f + 3; }
            }
            if (best >= 0.5f) {
                uint32_t key24 = conf_key24(best);
                uint32_t slot = atomicAdd(counter, 1u);
                if (slot < CAP) {
                    // ascending sort => conf desc then idx asc
                    list[slot] = ((unsigned long long)(0x1000000u - key24) << 25) |
                                 ((unsigned long long)(uint32_t)a << 7) |
                                 (unsigned long long)(uint32_t)lab;
                }
            }
        }
    }
}

// ---------- kernel 4: bitonic sort 4096 keys -> top-1024; fused prep (offsets/areas) ----------
__global__ __launch_bounds__(1024) void k_sortprep(const unsigned long long* __restrict__ list,
                                                   const int32_t* __restrict__ scal,
                                                   const float4* __restrict__ bboxes,
                                                   float4* __restrict__ topBox,
                                                   float* __restrict__ topConf,
                                                   float* __restrict__ topLab,
                                                   float4* __restrict__ ob,
                                                   float* __restrict__ area) {
    __shared__ unsigned long long sk[CAP];
    __shared__ float red[1024];
    const int t = threadIdx.x;
    uint32_t ncand = ((const uint32_t*)scal)[3];
    if (ncand > CAP) ncand = CAP;
    const uint32_t nsel = ((const uint32_t*)scal)[2];
    for (int i = t; i < CAP; i += 1024) sk[i] = (i < (int)ncand) ? list[i] : ~0ull;
    __syncthreads();
    for (int k = 2; k <= CAP; k <<= 1) {
        for (int j = k >> 1; j > 0; j >>= 1) {
            #pragma unroll
            for (int r0 = 0; r0 < 4; r0++) {
                int e = t + r0 * 1024;
                int p = e ^ j;
                if (p > e) {
                    unsigned long long x = sk[e], y = sk[p];
                    bool up = ((e & k) == 0);
                    if (up ? (x > y) : (x < y)) { sk[e] = y; sk[p] = x; }
                }
            }
            __syncthreads();
        }
    }
    unsigned long long s = sk[t];
    float4 bx = make_float4(0.f, 0.f, 0.f, 0.f);
    float cf = 0.f, lb = 0.f;
    if ((uint32_t)t < nsel) {
        uint32_t idx  = (uint32_t)(s >> 7) & 0x3FFFFu;      // < 262144 by construction
        uint32_t lab  = 127u - ((uint32_t)s & 127u);
        lab = 127u - lab;                                   // key stores raw lab (see k_cand)
        lab = (uint32_t)s & 127u;
        uint32_t keyp = (uint32_t)(s >> 25);
        cf = __uint_as_float(0x3F000000u + (0x1000000u - keyp));
        lb = (float)lab;
        bx = bboxes[idx];
    }
    topBox[t] = bx; topConf[t] = cf; topLab[t] = lb;
    // ---- fused prep: max_coord, offset boxes, areas (exact reference fp32 order) ----
    red[t] = fmaxf(fmaxf(bx.x, bx.y), fmaxf(bx.z, bx.w));
    __syncthreads();
    for (int off = 512; off > 0; off >>= 1) {
        if (t < off) red[t] = fmaxf(red[t], red[t + off]);
        __syncthreads();
    }
    float M = __fadd_rn(red[0], 1.0f);
    float o = __fmul_rn(lb, M);
    float4 q;
    q.x = __fadd_rn(bx.x, o); q.y = __fadd_rn(bx.y, o);
    q.z = __fadd_rn(bx.z, o); q.w = __fadd_rn(bx.w, o);
    ob[t] = q;
    area[t] = __fmul_rn(__fsub_rn(q.z, q.x), __fsub_rn(q.w, q.y));
}

// ---------- kernel 5: pairwise IoU suppression bit matrix ----------
__global__ __launch_bounds__(256) void k_mask(const float4* __restrict__ ob,
                                              const float* __restrict__ area,
                                              unsigned long long* __restrict__ mask) {
    __shared__ float4 sob[K_TOP];
    __shared__ float  sar[K_TOP];
    const int t = threadIdx.x, b = blockIdx.x;
    for (int i = t; i < K_TOP; i += 256) { sob[i] = ob[i]; sar[i] = area[i]; }
    __syncthreads();
    const int il = t >> 4;            // row within block (0..15)
    const int w  = t & 15;            // 64-bit word (0..15)
    const int i  = b * 16 + il;
    const float4 bi = sob[i];
    const float  ai = sar[i];
    unsigned long long word = 0;
    const int j0 = w * 64;
    #pragma unroll 8
    for (int bit = 0; bit < 64; bit++) {
        const int j = j0 + bit;
        if (j > i) {
            float4 bj = sob[j];
            float lx = fmaxf(bi.x, bj.x), ly = fmaxf(bi.y, bj.y);
            float rx = fminf(bi.z, bj.z), ry = fminf(bi.w, bj.w);
            float wx = fmaxf(__fsub_rn(rx, lx), 0.f);
            float wy = fmaxf(__fsub_rn(ry, ly), 0.f);
            float inter = __fmul_rn(wx, wy);
            float uni = __fsub_rn(__fadd_rn(ai, sar[j]), inter);
            float iou = __fdiv_rn(inter, fmaxf(uni, 1e-9f));
            if (iou > 0.6f) word |= 1ull << bit;
        }
    }
    mask[i * 16 + w] = word;
}

static __device__ __forceinline__ uint32_t rl32(uint32_t v, int lane) {
    return (uint32_t)__builtin_amdgcn_readlane((int)v, lane);
}

// ---------- kernel 6: LDS-staged serial greedy sweep + masked fp32 output ----------
__global__ __launch_bounds__(1024) void k_sweep(const unsigned long long* __restrict__ mask,
                                                const int32_t* __restrict__ scal,
                                                const float4* __restrict__ topBox,
                                                const float* __restrict__ topConf,
                                                const float* __restrict__ topLab,
                                                float* __restrict__ out) {
    __shared__ unsigned long long lds[256 * 16];   // 32 KB chunk of the bit matrix
    __shared__ unsigned long long keepw[16];
    const int t = threadIdx.x;
    const uint32_t nsel = ((const uint32_t*)scal)[2];
    unsigned long long kw = 0;
    if (t < 16) {
        int lo = t * 64;
        kw = (nsel >= (uint32_t)(lo + 64)) ? ~0ull
           : ((nsel <= (uint32_t)lo) ? 0ull : ((1ull << (nsel - lo)) - 1ull));
    }
    for (int c = 0; c < 4; c++) {
        const unsigned long long* src = mask + c * 4096;   // rows [256c, 256c+256)
        #pragma unroll
        for (int r = 0; r < 4; r++) lds[r * 1024 + t] = src[r * 1024 + t];
        __syncthreads();
        if (t < 16) {
            const int i0 = c * 256;
            #pragma unroll 8
            for (int i = i0; i < i0 + 256; i++) {
                // broadcast current keep word via readlane (uniform index -> scalar chain)
                const int wi = i >> 6;
                uint32_t lo32 = rl32((uint32_t)(kw & 0xFFFFFFFFull), wi);
                uint32_t hi32 = rl32((uint32_t)(kw >> 32), wi);
                unsigned long long cur = ((unsigned long long)hi32 << 32) | lo32;
                unsigned long long bi = (cur >> (i & 63)) & 1ull;
                unsigned long long m = lds[(i & 255) * 16 + t];   // bank 2t: conflict-free
                kw &= ~(m & (0ull - bi));
            }
        }
        __syncthreads();
    }
    if (t < 16) keepw[t] = kw;
    __syncthreads();
    const bool keep = (keepw[t >> 6] >> (t & 63)) & 1ull;
    float4 bx = topBox[t];
    float v0 = keep ? bx.x : 0.f, v1 = keep ? bx.y : 0.f;
    float v2 = keep ? bx.z : 0.f, v3 = keep ? bx.w : 0.f;
    float v4 = keep ? topConf[t] : 0.f, v5 = keep ? topLab[t] : 0.f;
    float2* o2 = (float2*)out;
    o2[t * 3 + 0] = make_float2(v0, v1);
    o2[t * 3 + 1] = make_float2(v2, v3);
    o2[t * 3 + 2] = make_float2(v4, v5);
}

extern "C" void kernel_launch(void* const* d_in, const int* in_sizes, int n_in,
                              void* d_out, int out_size, void* d_ws, size_t ws_size,
                              hipStream_t stream) {
    const float* bboxes = (const float*)d_in[0];
    const float* scores = (const float*)d_in[1];
    if (n_in >= 2 && in_sizes[0] > in_sizes[1]) {   // defensive: scores is the 20x larger input
        bboxes = (const float*)d_in[1];
        scores = (const float*)d_in[0];
    }
    char* ws = (char*)d_ws;

    if (ws_size < (size_t)WS_REQUIRED) {
        k_sentinel<<<(K_TOP * 6 + 255) / 256, 256, 0, stream>>>(
            (float*)d_out, (float)(ws_size >> 10));
        return;
    }

    int32_t*  scal    = (int32_t*)(ws + OFF_SCAL);
    uint32_t* hist    = (uint32_t*)(ws + OFF_HIST);
    uint16_t* bins16  = (uint16_t*)(ws + OFF_BINS);
    unsigned long long* list = (unsigned long long*)(ws + OFF_LIST);
    float4*   topBox  = (float4*)(ws + OFF_TB);
    float*    topConf = (float*)(ws + OFF_TC);
    float*    topLab  = (float*)(ws + OFF_TL);
    float4*   ob      = (float4*)(ws + OFF_OB);
    float*    area    = (float*)(ws + OFF_AREA);
    unsigned long long* mask = (unsigned long long*)(ws + OFF_MASK);

    k_zero    <<<129,          256, 0, stream>>>((uint32_t*)ws);
    k_conf    <<<N_ANCH / 64,  256, 0, stream>>>(scores, bins16, hist);
    k_scan    <<<1,           1024, 0, stream>>>(hist, scal);
    k_cand    <<<128,          256, 0, stream>>>(scores, bins16, scal,
                                                 (uint32_t*)&scal[3], list);
    k_sortprep<<<1,           1024, 0, stream>>>(list, scal, (const float4*)bboxes,
                                                 topBox, topConf, topLab, ob, area);
    k_mask    <<<64,           256, 0, stream>>>(ob, area, mask);
    k_sweep   <<<1,           1024, 0, stream>>>(mask, scal, topBox, topConf, topLab,
                                                 (float*)d_out);
}